// Round 5
// baseline (365.505 us; speedup 1.0000x reference)
//
#include <hip/hip_runtime.h>

// PWC-Net 9x9 correlation via bf16 MFMA, staging restructured (R5).
// R4 post-mortem: 8 channel-strided scalar global loads per staged slot ->
// serialized at ~84 VGPRs -> 204 us with MfmaUtil 2.4%. Fix: coalesced
// x-contiguous float4 staging (2 loads/slot), transpose on the LDS side:
// LDS holds bf16 channel-PAIR dwords in [row][cpair][x] layout, so an MFMA
// fragment (8 consecutive channels) = 4 x ds_read_b32 at constant offsets
// (fusable ds_read2_b32). launch_bounds(384,2): 256-reg cap, acc in AGPRs.
//
// Tile: block = (b, 8y, 16x), all 81 displacements. 6 waves = ygrp(2)x dygrp(3);
// wave: 4y x 3dy x 2nh = 24 mfma tiles (96 acc regs).
// A: 8y x 16x x 32c per chunk; B: 16ys x 32xs x 32c (xs in [x0-4, x0+28), all
// global float4 16B-aligned since x0 % 16 == 0).

typedef __attribute__((ext_vector_type(8))) short bf16x8;
typedef __attribute__((ext_vector_type(4))) float f32x4;

namespace {
constexpr int kC = 128, kH = 112, kW = 192;
constexpr int kHW = kH * kW;                    // 21504
constexpr long long kCHW = (long long)kC * kHW;
constexpr int YT = 8;                           // output rows per block
constexpr int XT = 16;                          // x per block (M)
constexpr int KC = 32;                          // channels per chunk
constexpr int NT = 384;                         // 6 waves
// LDS dword layouts (per chunk), dword = (bf16 ch 2i, bf16 ch 2i+1):
// A[y<8][cpair<16][x<16]   -> 2048 dwords (8 KB)
// B[ys<16][cpair<16][xs<32] -> 8192 dwords (32 KB); xs_local = xs_g-(x0-4)
constexpr int A_DW = 8 * 16 * 16;
constexpr int B_DW = 16 * 16 * 32;
}  // namespace

__device__ __forceinline__ unsigned pack2_bf16(float a, float b) {
  unsigned ua = __float_as_uint(a) + 0x8000u;   // round-to-nearest-ish
  unsigned ub = __float_as_uint(b) + 0x8000u;
  return (ua >> 16) | (ub & 0xffff0000u);
}

__global__ __launch_bounds__(NT, 2)
void corr81_mfma(const float* __restrict__ first,
                 const float* __restrict__ second,
                 float* __restrict__ out) {
  __shared__ unsigned lds32[A_DW + B_DW];       // 40 KB

  const int g = blockIdx.x;
  const int b = g & 7;                  // batch -> XCD slab
  const int i = g >> 3;
  const int yt = i % (kH / YT);         // yt innermost: S-row L2 sliding window
  const int xt = i / (kH / YT);
  const int x0 = xt * XT, y0 = yt * YT;

  const int tid = threadIdx.x;
  const int lane = tid & 63;
  const int wv = tid >> 6;              // 0..5
  const int dy_w = (wv % 3) * 3;        // dy group base: 0,3,6
  const int y_w = (wv / 3) * 4;         // y group base: 0,4
  const int col = lane & 15;
  const int q = lane >> 4;

  f32x4 acc[4][3][2];
#pragma unroll
  for (int yy = 0; yy < 4; ++yy)
#pragma unroll
    for (int dd = 0; dd < 3; ++dd)
#pragma unroll
      for (int nh = 0; nh < 2; ++nh) acc[yy][dd][nh] = (f32x4){0.f, 0.f, 0.f, 0.f};

  const float* fb = first + (long long)b * kCHW;
  const float* sb = second + (long long)b * kCHW;

  for (int ck = 0; ck < kC / KC; ++ck) {
    const int c0 = ck * KC;
    __syncthreads();  // previous chunk's frag reads complete

    // ---- A staging: 512 slots (xq 0..3, y 0..7, cpair 0..15) ----
#pragma unroll
    for (int k = 0; k < 2; ++k) {
      const int s = tid + k * NT;
      if (s < 512) {                     // wave-uniform (512 = 8*64)
        const int xq = s & 3, y = (s >> 2) & 7, cp = s >> 5;
        const float* p = fb + (long long)(c0 + 2 * cp) * kHW +
                         (y0 + y) * kW + x0 + xq * 4;
        const float4 a = *(const float4*)p;
        const float4 c = *(const float4*)(p + kHW);
        uint4 w;
        w.x = pack2_bf16(a.x, c.x);
        w.y = pack2_bf16(a.y, c.y);
        w.z = pack2_bf16(a.z, c.z);
        w.w = pack2_bf16(a.w, c.w);
        *(uint4*)&lds32[(y * 16 + cp) * 16 + xq * 4] = w;
      }
    }

    // ---- B staging: 2048 slots (xq 0..7, ys 0..15, cpair 0..15) ----
#pragma unroll
    for (int k = 0; k < 6; ++k) {
      const int s = tid + k * NT;
      if (s < 2048) {                    // wave-uniform (2048 = 32*64)
        const int xq = s & 7, ys = (s >> 3) & 15, cp = s >> 7;
        const int ysg = y0 + ys - 4;
        const int xsg = x0 - 4 + xq * 4;  // 4-aligned; quad fully in or out
        uint4 w = make_uint4(0u, 0u, 0u, 0u);
        if ((unsigned)ysg < (unsigned)kH && (unsigned)xsg < (unsigned)kW) {
          const float* p = sb + (long long)(c0 + 2 * cp) * kHW +
                           ysg * kW + xsg;
          const float4 a = *(const float4*)p;
          const float4 c = *(const float4*)(p + kHW);
          w.x = pack2_bf16(a.x, c.x);
          w.y = pack2_bf16(a.y, c.y);
          w.z = pack2_bf16(a.z, c.z);
          w.w = pack2_bf16(a.w, c.w);
        }
        *(uint4*)&lds32[A_DW + (ys * 16 + cp) * 32 + xq * 4] = w;
      }
    }
    __syncthreads();

    // ---- fragment reads (4 x b32 each, constant offsets) + 24 mfma ----
    bf16x8 aF[4];
#pragma unroll
    for (int yy = 0; yy < 4; ++yy) {
      const int base = ((y_w + yy) * 16 + q * 4) * 16 + col;
      uint4 v;
      v.x = lds32[base];
      v.y = lds32[base + 16];
      v.z = lds32[base + 32];
      v.w = lds32[base + 48];
      aF[yy] = __builtin_bit_cast(bf16x8, v);
    }
    const int sbase = y_w + dy_w;  // B row for (yy,dd) is sbase + yy + dd
#pragma unroll
    for (int nh = 0; nh < 2; ++nh) {
      bf16x8 bF[6];
#pragma unroll
      for (int si = 0; si < 6; ++si) {
        const int base = A_DW + ((sbase + si) * 16 + q * 4) * 32 + nh * 16 + col;
        uint4 v;
        v.x = lds32[base];
        v.y = lds32[base + 32];
        v.z = lds32[base + 64];
        v.w = lds32[base + 96];
        bF[si] = __builtin_bit_cast(bf16x8, v);
      }
#pragma unroll
      for (int yy = 0; yy < 4; ++yy)
#pragma unroll
        for (int dd = 0; dd < 3; ++dd)
          acc[yy][dd][nh] = __builtin_amdgcn_mfma_f32_16x16x32_bf16(
              aF[yy], bF[yy + dd], acc[yy][dd][nh], 0, 0, 0);
    }
  }

  // ---- epilogue (verified in R4): D[m=x][n=xs]; dx = n_global - m ----
  const float scale = 1.f / 128.f;
#pragma unroll
  for (int nh = 0; nh < 2; ++nh)
#pragma unroll
    for (int r = 0; r < 4; ++r) {
      const int xloc = q * 4 + r;
      const int d = nh * 16 + col - xloc;  // dx index = dx+4
      if ((unsigned)d <= 8u) {
#pragma unroll
        for (int yy = 0; yy < 4; ++yy)
#pragma unroll
          for (int dd = 0; dd < 3; ++dd) {
            const int ch = (dy_w + dd) * 9 + d;
            const long long o =
                (((long long)b * 81 + ch) * kH + (y0 + y_w + yy)) *
                    (long long)kW +
                (x0 + xloc);
            out[o] = acc[yy][dd][nh][r] * scale;
          }
      }
    }
}

extern "C" void kernel_launch(void* const* d_in, const int* in_sizes, int n_in,
                              void* d_out, int out_size, void* d_ws, size_t ws_size,
                              hipStream_t stream) {
  const float* first = (const float*)d_in[0];
  const float* second = (const float*)d_in[1];
  float* out = (float*)d_out;

  const int grid = 8 * (kH / YT) * (kW / XT);  // 8*14*12 = 1344
  corr81_mfma<<<grid, NT, 0, stream>>>(first, second, out);
}